// Round 1
// baseline (2903.567 us; speedup 1.0000x reference)
//
#include <hip/hip_runtime.h>
#include <math.h>

#define B_ 16
#define S_ 1024
#define D_ 1024
#define NH_ 16
#define M_TOT (B_ * S_)

// ---------------------------------------------------------------- RoPE tables
// cos1/sin1: [1024][8]  angle = s * 10000^(-i/8)
// cos2/sin2: [32][12]   angle = p * 10000^(-j/12)   (x and y tables identical)
__global__ void build_tables(float* __restrict__ cos1, float* __restrict__ sin1,
                             float* __restrict__ cos2, float* __restrict__ sin2) {
  int t = blockIdx.x * 256 + threadIdx.x;
  if (t < S_ * 8) {
    int s = t >> 3, i = t & 7;
    double ang = (double)s * pow(10000.0, -(double)i / 8.0);
    cos1[t] = (float)cos(ang);
    sin1[t] = (float)sin(ang);
  } else if (t < S_ * 8 + 384) {
    int u = t - S_ * 8;
    int p = u / 12, j = u - p * 12;
    double ang = (double)p * pow(10000.0, -(double)j / 12.0);
    cos2[u] = (float)cos(ang);
    sin2[u] = (float)sin(ang);
  }
}

// ---------------------------------------------------------------- GEMM
// C[M,1024] = A[M,1024] @ W[1024,1024]^T + bias   (128x128 tile, BK=16, 8x8/thread)
__global__ __launch_bounds__(256) void gemm_bias(
    const float* __restrict__ A, const float* __restrict__ W,
    const float* __restrict__ bias, float* __restrict__ C) {
  __shared__ float As[16][132];  // [k][row] transposed
  __shared__ float Bs[16][132];
  const int t  = threadIdx.x;
  const int tx = t & 15, ty = t >> 4;
  const int n0 = blockIdx.x * 128;
  const int m0 = blockIdx.y * 128;
  const int lr = t >> 2;          // 0..63
  const int lk = (t & 3) << 2;    // 0,4,8,12
  const float* Ap = A + (size_t)(m0 + lr) * D_ + lk;
  const float* Wp = W + (size_t)(n0 + lr) * D_ + lk;
  float acc[8][8];
#pragma unroll
  for (int i = 0; i < 8; ++i)
#pragma unroll
    for (int j = 0; j < 8; ++j) acc[i][j] = 0.f;

  for (int k0 = 0; k0 < D_; k0 += 16) {
    float4 a0 = *(const float4*)(Ap + k0);
    float4 a1 = *(const float4*)(Ap + k0 + (size_t)64 * D_);
    float4 b0 = *(const float4*)(Wp + k0);
    float4 b1 = *(const float4*)(Wp + k0 + (size_t)64 * D_);
    __syncthreads();
    As[lk + 0][lr] = a0.x; As[lk + 1][lr] = a0.y;
    As[lk + 2][lr] = a0.z; As[lk + 3][lr] = a0.w;
    As[lk + 0][lr + 64] = a1.x; As[lk + 1][lr + 64] = a1.y;
    As[lk + 2][lr + 64] = a1.z; As[lk + 3][lr + 64] = a1.w;
    Bs[lk + 0][lr] = b0.x; Bs[lk + 1][lr] = b0.y;
    Bs[lk + 2][lr] = b0.z; Bs[lk + 3][lr] = b0.w;
    Bs[lk + 0][lr + 64] = b1.x; Bs[lk + 1][lr + 64] = b1.y;
    Bs[lk + 2][lr + 64] = b1.z; Bs[lk + 3][lr + 64] = b1.w;
    __syncthreads();
#pragma unroll
    for (int kk = 0; kk < 16; ++kk) {
      float4 av0 = *(const float4*)&As[kk][ty * 8];
      float4 av1 = *(const float4*)&As[kk][ty * 8 + 4];
      float4 bv0 = *(const float4*)&Bs[kk][tx * 4];        // cols tx*4..+3
      float4 bv1 = *(const float4*)&Bs[kk][tx * 4 + 64];   // cols 64+tx*4..+3
      float a[8] = {av0.x, av0.y, av0.z, av0.w, av1.x, av1.y, av1.z, av1.w};
      float b[8] = {bv0.x, bv0.y, bv0.z, bv0.w, bv1.x, bv1.y, bv1.z, bv1.w};
#pragma unroll
      for (int i = 0; i < 8; ++i)
#pragma unroll
        for (int j = 0; j < 8; ++j) acc[i][j] = fmaf(a[i], b[j], acc[i][j]);
    }
  }
#pragma unroll
  for (int i = 0; i < 8; ++i) {
    const size_t m = (size_t)(m0 + ty * 8 + i);
    float4 o0, o1;
    o0.x = acc[i][0] + bias[n0 + tx * 4 + 0];
    o0.y = acc[i][1] + bias[n0 + tx * 4 + 1];
    o0.z = acc[i][2] + bias[n0 + tx * 4 + 2];
    o0.w = acc[i][3] + bias[n0 + tx * 4 + 3];
    o1.x = acc[i][4] + bias[n0 + 64 + tx * 4 + 0];
    o1.y = acc[i][5] + bias[n0 + 64 + tx * 4 + 1];
    o1.z = acc[i][6] + bias[n0 + 64 + tx * 4 + 2];
    o1.w = acc[i][7] + bias[n0 + 64 + tx * 4 + 3];
    *(float4*)(C + m * D_ + n0 + tx * 4)      = o0;
    *(float4*)(C + m * D_ + n0 + 64 + tx * 4) = o1;
  }
}

// ---------------------------------------------------------------- RoPE (in place)
// one thread per rotation pair; per head: 8 latent pairs, 12 x-pairs, 12 y-pairs
__global__ __launch_bounds__(256) void rope_kernel(
    float* q, const float* __restrict__ cos1, const float* __restrict__ sin1,
    const float* __restrict__ cos2, const float* __restrict__ sin2) {
  int tid = blockIdx.x * 256 + threadIdx.x;   // < 16384*512
  int u = tid & 511;
  int m = tid >> 9;
  int s = m & (S_ - 1);
  int head = u >> 5, w = u & 31;
  size_t base = (size_t)m * D_ + head * 64;
  size_t c0, c1;
  float cv, sv;
  if (w < 8) {                       // latent 1D: pairs (2i, 2i+1)
    c0 = base + 2 * w; c1 = c0 + 1;
    cv = cos1[s * 8 + w]; sv = sin1[s * 8 + w];
  } else if (w < 20) {               // spatial x: (16+j, 28+j)
    int j = w - 8, x = s & 31;
    c0 = base + 16 + j; c1 = base + 28 + j;
    cv = cos2[x * 12 + j]; sv = sin2[x * 12 + j];
  } else {                           // spatial y: (40+j, 52+j)
    int j = w - 20, y = s >> 5;
    c0 = base + 40 + j; c1 = base + 52 + j;
    cv = cos2[y * 12 + j]; sv = sin2[y * 12 + j];
  }
  float a = q[c0], b = q[c1];
  q[c0] = a * cv - b * sv;
  q[c1] = a * sv + b * cv;
}

// ---------------------------------------------------------------- flash attention
// block = (qt, head, batch); 64 query rows; K/V tiles of 64; online softmax.
// o may alias q: each block writes exactly the (rows,cols) region only it reads.
__global__ __launch_bounds__(256) void attn_kernel(
    const float* q, const float* k, const float* v, float* o) {
  __shared__ float Qt[64][68];   // [kdim][row] transposed
  __shared__ float KV[64][68];   // K phase: [kdim][col] ; V phase: [row][col]
  __shared__ float Ss[64][65];   // scores / probabilities
  __shared__ float mrow[64], lrow[64], arow[64];
  const int t = threadIdx.x;
  const int tx = t & 15, ty = t >> 4;
  const int qt = blockIdx.x, n = blockIdx.y, b = blockIdx.z;
  const size_t m0 = (size_t)b * S_ + qt * 64;
  const int n0 = n * 64;
  // stage Q transposed
#pragma unroll
  for (int rep = 0; rep < 4; ++rep) {
    int f = t + rep * 256;
    int r = f >> 4, c4 = (f & 15) << 2;
    float4 val = *(const float4*)(q + (m0 + r) * D_ + n0 + c4);
    Qt[c4 + 0][r] = val.x; Qt[c4 + 1][r] = val.y;
    Qt[c4 + 2][r] = val.z; Qt[c4 + 3][r] = val.w;
  }
  if (t < 64) { mrow[t] = -INFINITY; lrow[t] = 0.f; }
  float O[4][4];
#pragma unroll
  for (int i = 0; i < 4; ++i)
#pragma unroll
    for (int j = 0; j < 4; ++j) O[i][j] = 0.f;

  for (int kt = 0; kt < 16; ++kt) {
    const size_t kb = (size_t)b * S_ + kt * 64;
    __syncthreads();   // prev PV done (KV free); covers Q/m/l init on kt==0
    // stage K transposed
#pragma unroll
    for (int rep = 0; rep < 4; ++rep) {
      int f = t + rep * 256;
      int r = f >> 4, c4 = (f & 15) << 2;
      float4 val = *(const float4*)(k + (kb + r) * D_ + n0 + c4);
      KV[c4 + 0][r] = val.x; KV[c4 + 1][r] = val.y;
      KV[c4 + 2][r] = val.z; KV[c4 + 3][r] = val.w;
    }
    __syncthreads();
    // scores: rows ty*4+i, cols tx*4+j
    float sc[4][4];
#pragma unroll
    for (int i = 0; i < 4; ++i)
#pragma unroll
      for (int j = 0; j < 4; ++j) sc[i][j] = 0.f;
#pragma unroll 8
    for (int kk = 0; kk < 64; ++kk) {
      float4 qv = *(const float4*)&Qt[kk][ty * 4];
      float4 kv = *(const float4*)&KV[kk][tx * 4];
      float qa[4] = {qv.x, qv.y, qv.z, qv.w};
      float ka[4] = {kv.x, kv.y, kv.z, kv.w};
#pragma unroll
      for (int i = 0; i < 4; ++i)
#pragma unroll
        for (int j = 0; j < 4; ++j) sc[i][j] = fmaf(qa[i], ka[j], sc[i][j]);
    }
#pragma unroll
    for (int i = 0; i < 4; ++i)
#pragma unroll
      for (int j = 0; j < 4; ++j)
        Ss[ty * 4 + i][tx * 4 + j] = sc[i][j] * 0.125f;
    __syncthreads();   // scores written, K reads done
    // stage V row-major over K (all threads) — overlaps with wave-0 row pass
#pragma unroll
    for (int rep = 0; rep < 4; ++rep) {
      int f = t + rep * 256;
      int r = f >> 4, c4 = (f & 15) << 2;
      float4 val = *(const float4*)(v + (kb + r) * D_ + n0 + c4);
      *(float4*)&KV[r][c4] = val;
    }
    // online-softmax row pass (wave 0)
    if (t < 64) {
      const int r = t;
      float om = mrow[r];
      float rm = -INFINITY;
#pragma unroll 8
      for (int j = 0; j < 64; ++j) rm = fmaxf(rm, Ss[r][j]);
      float nm = fmaxf(om, rm);
      float a = __expf(om - nm);
      float sum = 0.f;
#pragma unroll 8
      for (int j = 0; j < 64; ++j) {
        float p = __expf(Ss[r][j] - nm);
        Ss[r][j] = p;
        sum += p;
      }
      lrow[r] = a * lrow[r] + sum;
      mrow[r] = nm;
      arow[r] = a;
    }
    __syncthreads();
    // rescale + PV
    float al[4];
#pragma unroll
    for (int i = 0; i < 4; ++i) al[i] = arow[ty * 4 + i];
#pragma unroll
    for (int i = 0; i < 4; ++i)
#pragma unroll
      for (int j = 0; j < 4; ++j) O[i][j] *= al[i];
#pragma unroll 4
    for (int jk = 0; jk < 64; ++jk) {
      float4 vv = *(const float4*)&KV[jk][tx * 4];
      float va[4] = {vv.x, vv.y, vv.z, vv.w};
#pragma unroll
      for (int i = 0; i < 4; ++i) {
        float p = Ss[ty * 4 + i][jk];
#pragma unroll
        for (int j = 0; j < 4; ++j) O[i][j] = fmaf(p, va[j], O[i][j]);
      }
    }
  }
  // epilogue: normalize and store
  float inv[4];
#pragma unroll
  for (int i = 0; i < 4; ++i) inv[i] = 1.0f / lrow[ty * 4 + i];
#pragma unroll
  for (int i = 0; i < 4; ++i) {
    float4 res;
    res.x = O[i][0] * inv[i];
    res.y = O[i][1] * inv[i];
    res.z = O[i][2] * inv[i];
    res.w = O[i][3] * inv[i];
    *(float4*)(o + (m0 + ty * 4 + i) * D_ + n0 + tx * 4) = res;
  }
}

// ---------------------------------------------------------------- launch
extern "C" void kernel_launch(void* const* d_in, const int* in_sizes, int n_in,
                              void* d_out, int out_size, void* d_ws, size_t ws_size,
                              hipStream_t stream) {
  const float* x  = (const float*)d_in[0];
  const float* Wq = (const float*)d_in[1];
  const float* bq = (const float*)d_in[2];
  const float* Wk = (const float*)d_in[3];
  const float* bk = (const float*)d_in[4];
  const float* Wv = (const float*)d_in[5];
  const float* bv = (const float*)d_in[6];
  const float* Wo = (const float*)d_in[7];
  const float* bo = (const float*)d_in[8];
  float* out = (float*)d_out;

  char* ws = (char*)d_ws;
  const size_t SZ = (size_t)M_TOT * D_ * sizeof(float);   // 64 MB
  float* q = (float*)(ws);              // reused as attention output
  float* kbuf = (float*)(ws + SZ);
  float* vbuf = (float*)(ws + 2 * SZ);
  float* cos1 = (float*)(ws + 3 * SZ);
  float* sin1 = cos1 + S_ * 8;
  float* cos2 = sin1 + S_ * 8;
  float* sin2 = cos2 + 384;

  build_tables<<<34, 256, 0, stream>>>(cos1, sin1, cos2, sin2);

  dim3 ggrid(D_ / 128, M_TOT / 128);
  gemm_bias<<<ggrid, 256, 0, stream>>>(x, Wq, bq, q);
  gemm_bias<<<ggrid, 256, 0, stream>>>(x, Wk, bk, kbuf);
  gemm_bias<<<ggrid, 256, 0, stream>>>(x, Wv, bv, vbuf);

  const int rope_blocks = (M_TOT * 512) / 256;   // 32768
  rope_kernel<<<rope_blocks, 256, 0, stream>>>(q, cos1, sin1, cos2, sin2);
  rope_kernel<<<rope_blocks, 256, 0, stream>>>(kbuf, cos1, sin1, cos2, sin2);

  attn_kernel<<<dim3(S_ / 64, NH_, B_), 256, 0, stream>>>(q, kbuf, vbuf, q);

  gemm_bias<<<ggrid, 256, 0, stream>>>(q, Wo, bo, out);
}

// Round 3
// 2018.849 us; speedup vs baseline: 1.4382x; 1.4382x over previous
//
#include <hip/hip_runtime.h>
#include <math.h>

#define B_ 16
#define S_ 1024
#define D_ 1024
#define NH_ 16
#define M_TOT (B_ * S_)

typedef __attribute__((ext_vector_type(8))) short short8v;
typedef __attribute__((ext_vector_type(4))) short short4v;
typedef __attribute__((ext_vector_type(4))) float float4v;

static __device__ __forceinline__ unsigned short f2bf(float f) {
  union { float f; unsigned u; } x; x.f = f;
  unsigned r = (x.u + 0x7fffu + ((x.u >> 16) & 1u)) >> 16;
  return (unsigned short)r;
}
static __device__ __forceinline__ float bf2f(unsigned short u) {
  union { unsigned u; float f; } x; x.u = ((unsigned)u) << 16;
  return x.f;
}

// ---------------------------------------------------------------- RoPE tables
__global__ void build_tables(float* __restrict__ cos1, float* __restrict__ sin1,
                             float* __restrict__ cos2, float* __restrict__ sin2) {
  int t = blockIdx.x * 256 + threadIdx.x;
  if (t < S_ * 8) {
    int s = t >> 3, i = t & 7;
    double ang = (double)s * pow(10000.0, -(double)i / 8.0);
    cos1[t] = (float)cos(ang);
    sin1[t] = (float)sin(ang);
  } else if (t < S_ * 8 + 384) {
    int u = t - S_ * 8;
    int p = u / 12, j = u - p * 12;
    double ang = (double)p * pow(10000.0, -(double)j / 12.0);
    cos2[u] = (float)cos(ang);
    sin2[u] = (float)sin(ang);
  }
}

// ---------------------------------------------------------------- GEMM fp32->fp32
// C[M,1024] = A[M,1024] @ W[1024,1024]^T + bias   (128x128 tile, BK=16, 8x8/thread)
__global__ __launch_bounds__(256) void gemm_bias(
    const float* __restrict__ A, const float* __restrict__ W,
    const float* __restrict__ bias, float* __restrict__ C) {
  __shared__ float As[16][132];
  __shared__ float Bs[16][132];
  const int t  = threadIdx.x;
  const int tx = t & 15, ty = t >> 4;
  const int n0 = blockIdx.x * 128;
  const int m0 = blockIdx.y * 128;
  const int lr = t >> 2;
  const int lk = (t & 3) << 2;
  const float* Ap = A + (size_t)(m0 + lr) * D_ + lk;
  const float* Wp = W + (size_t)(n0 + lr) * D_ + lk;
  float acc[8][8];
#pragma unroll
  for (int i = 0; i < 8; ++i)
#pragma unroll
    for (int j = 0; j < 8; ++j) acc[i][j] = 0.f;

  for (int k0 = 0; k0 < D_; k0 += 16) {
    float4 a0 = *(const float4*)(Ap + k0);
    float4 a1 = *(const float4*)(Ap + k0 + (size_t)64 * D_);
    float4 b0 = *(const float4*)(Wp + k0);
    float4 b1 = *(const float4*)(Wp + k0 + (size_t)64 * D_);
    __syncthreads();
    As[lk + 0][lr] = a0.x; As[lk + 1][lr] = a0.y;
    As[lk + 2][lr] = a0.z; As[lk + 3][lr] = a0.w;
    As[lk + 0][lr + 64] = a1.x; As[lk + 1][lr + 64] = a1.y;
    As[lk + 2][lr + 64] = a1.z; As[lk + 3][lr + 64] = a1.w;
    Bs[lk + 0][lr] = b0.x; Bs[lk + 1][lr] = b0.y;
    Bs[lk + 2][lr] = b0.z; Bs[lk + 3][lr] = b0.w;
    Bs[lk + 0][lr + 64] = b1.x; Bs[lk + 1][lr + 64] = b1.y;
    Bs[lk + 2][lr + 64] = b1.z; Bs[lk + 3][lr + 64] = b1.w;
    __syncthreads();
#pragma unroll
    for (int kk = 0; kk < 16; ++kk) {
      float4 av0 = *(const float4*)&As[kk][ty * 8];
      float4 av1 = *(const float4*)&As[kk][ty * 8 + 4];
      float4 bv0 = *(const float4*)&Bs[kk][tx * 4];
      float4 bv1 = *(const float4*)&Bs[kk][tx * 4 + 64];
      float a[8] = {av0.x, av0.y, av0.z, av0.w, av1.x, av1.y, av1.z, av1.w};
      float b[8] = {bv0.x, bv0.y, bv0.z, bv0.w, bv1.x, bv1.y, bv1.z, bv1.w};
#pragma unroll
      for (int i = 0; i < 8; ++i)
#pragma unroll
        for (int j = 0; j < 8; ++j) acc[i][j] = fmaf(a[i], b[j], acc[i][j]);
    }
  }
#pragma unroll
  for (int i = 0; i < 8; ++i) {
    const size_t m = (size_t)(m0 + ty * 8 + i);
    float4 o0, o1;
    o0.x = acc[i][0] + bias[n0 + tx * 4 + 0];
    o0.y = acc[i][1] + bias[n0 + tx * 4 + 1];
    o0.z = acc[i][2] + bias[n0 + tx * 4 + 2];
    o0.w = acc[i][3] + bias[n0 + tx * 4 + 3];
    o1.x = acc[i][4] + bias[n0 + 64 + tx * 4 + 0];
    o1.y = acc[i][5] + bias[n0 + 64 + tx * 4 + 1];
    o1.z = acc[i][6] + bias[n0 + 64 + tx * 4 + 2];
    o1.w = acc[i][7] + bias[n0 + 64 + tx * 4 + 3];
    *(float4*)(C + m * D_ + n0 + tx * 4)      = o0;
    *(float4*)(C + m * D_ + n0 + 64 + tx * 4) = o1;
  }
}

// ---------------------------------------------------------------- GEMM fp32->bf16
__global__ __launch_bounds__(256) void gemm_bias_bf16(
    const float* __restrict__ A, const float* __restrict__ W,
    const float* __restrict__ bias, unsigned short* __restrict__ C) {
  __shared__ float As[16][132];
  __shared__ float Bs[16][132];
  const int t  = threadIdx.x;
  const int tx = t & 15, ty = t >> 4;
  const int n0 = blockIdx.x * 128;
  const int m0 = blockIdx.y * 128;
  const int lr = t >> 2;
  const int lk = (t & 3) << 2;
  const float* Ap = A + (size_t)(m0 + lr) * D_ + lk;
  const float* Wp = W + (size_t)(n0 + lr) * D_ + lk;
  float acc[8][8];
#pragma unroll
  for (int i = 0; i < 8; ++i)
#pragma unroll
    for (int j = 0; j < 8; ++j) acc[i][j] = 0.f;

  for (int k0 = 0; k0 < D_; k0 += 16) {
    float4 a0 = *(const float4*)(Ap + k0);
    float4 a1 = *(const float4*)(Ap + k0 + (size_t)64 * D_);
    float4 b0 = *(const float4*)(Wp + k0);
    float4 b1 = *(const float4*)(Wp + k0 + (size_t)64 * D_);
    __syncthreads();
    As[lk + 0][lr] = a0.x; As[lk + 1][lr] = a0.y;
    As[lk + 2][lr] = a0.z; As[lk + 3][lr] = a0.w;
    As[lk + 0][lr + 64] = a1.x; As[lk + 1][lr + 64] = a1.y;
    As[lk + 2][lr + 64] = a1.z; As[lk + 3][lr + 64] = a1.w;
    Bs[lk + 0][lr] = b0.x; Bs[lk + 1][lr] = b0.y;
    Bs[lk + 2][lr] = b0.z; Bs[lk + 3][lr] = b0.w;
    Bs[lk + 0][lr + 64] = b1.x; Bs[lk + 1][lr + 64] = b1.y;
    Bs[lk + 2][lr + 64] = b1.z; Bs[lk + 3][lr + 64] = b1.w;
    __syncthreads();
#pragma unroll
    for (int kk = 0; kk < 16; ++kk) {
      float4 av0 = *(const float4*)&As[kk][ty * 8];
      float4 av1 = *(const float4*)&As[kk][ty * 8 + 4];
      float4 bv0 = *(const float4*)&Bs[kk][tx * 4];
      float4 bv1 = *(const float4*)&Bs[kk][tx * 4 + 64];
      float a[8] = {av0.x, av0.y, av0.z, av0.w, av1.x, av1.y, av1.z, av1.w};
      float b[8] = {bv0.x, bv0.y, bv0.z, bv0.w, bv1.x, bv1.y, bv1.z, bv1.w};
#pragma unroll
      for (int i = 0; i < 8; ++i)
#pragma unroll
        for (int j = 0; j < 8; ++j) acc[i][j] = fmaf(a[i], b[j], acc[i][j]);
    }
  }
#pragma unroll
  for (int i = 0; i < 8; ++i) {
    const size_t m = (size_t)(m0 + ty * 8 + i);
    unsigned short t0[4], t1[4];
#pragma unroll
    for (int j = 0; j < 4; ++j) {
      t0[j] = f2bf(acc[i][j]     + bias[n0 + tx * 4 + j]);
      t1[j] = f2bf(acc[i][4 + j] + bias[n0 + 64 + tx * 4 + j]);
    }
    *(short4v*)(C + m * D_ + n0 + tx * 4)      = *(short4v*)t0;
    *(short4v*)(C + m * D_ + n0 + 64 + tx * 4) = *(short4v*)t1;
  }
}

// ---------------------------------------------------------------- RoPE in place (bf16)
// one thread per rotation pair; fp32 math inside; optional scale (q: 0.125 exact).
__global__ __launch_bounds__(256) void rope_inplace(
    unsigned short* q,
    const float* __restrict__ cos1, const float* __restrict__ sin1,
    const float* __restrict__ cos2, const float* __restrict__ sin2,
    float scale) {
  int tid = blockIdx.x * 256 + threadIdx.x;
  int u = tid & 511;
  int m = tid >> 9;
  int s = m & (S_ - 1);
  int head = u >> 5, w = u & 31;
  size_t base = (size_t)m * D_ + head * 64;
  size_t c0, c1;
  float cv, sv;
  if (w < 8) {
    c0 = base + 2 * w; c1 = c0 + 1;
    cv = cos1[s * 8 + w]; sv = sin1[s * 8 + w];
  } else if (w < 20) {
    int j = w - 8, x = s & 31;
    c0 = base + 16 + j; c1 = base + 28 + j;
    cv = cos2[x * 12 + j]; sv = sin2[x * 12 + j];
  } else {
    int j = w - 20, y = s >> 5;
    c0 = base + 40 + j; c1 = base + 52 + j;
    cv = cos2[y * 12 + j]; sv = sin2[y * 12 + j];
  }
  float a = bf2f(q[c0]), b = bf2f(q[c1]);
  q[c0] = f2bf((a * cv - b * sv) * scale);
  q[c1] = f2bf((a * sv + b * cv) * scale);
}

// ---------------------------------------------------------------- V transpose (bf16)
// vb [b][s][head*64+n]  ->  vT [b][head][n(64)][s(1024)]
__global__ __launch_bounds__(256) void v_transpose(
    const unsigned short* __restrict__ v, unsigned short* __restrict__ vT) {
  __shared__ unsigned short T[64][72];
  const int t = threadIdx.x;
  const int st0 = blockIdx.x * 64;
  const int hd = blockIdx.y, b = blockIdx.z;
  const unsigned short* src = v + ((size_t)b * S_ + st0) * D_ + hd * 64;
#pragma unroll
  for (int rep = 0; rep < 4; ++rep) {
    int id = t + rep * 256;           // 0..1023
    int s = id >> 4, n4 = (id & 15) * 4;
    short4v val = *(const short4v*)(src + (size_t)s * D_ + n4);
    T[n4 + 0][s] = val[0]; T[n4 + 1][s] = val[1];
    T[n4 + 2][s] = val[2]; T[n4 + 3][s] = val[3];
  }
  __syncthreads();
  unsigned short* dst = vT + ((size_t)(b * NH_ + hd) * 64) * S_ + st0;
#pragma unroll
  for (int rep = 0; rep < 2; ++rep) {
    int id = t + rep * 256;           // 0..511
    int n = id >> 3, s8 = (id & 7) * 8;
    unsigned short tmp[8];
#pragma unroll
    for (int u2 = 0; u2 < 8; ++u2) tmp[u2] = T[n][s8 + u2];
    *(short8v*)(dst + (size_t)n * S_ + s8) = *(short8v*)tmp;
  }
}

// ---------------------------------------------------------------- MFMA flash attention
// block = (qt 0..7, head, batch); 4 waves x 32 q-rows = 128-row Q tile; K-tiles of 64.
// 16x16x32 bf16 MFMA. A[m=lane&15][k=(lane>>4)*8+j]; C/D col=lane&15,row=(lane>>4)*4+reg.
// Online softmax fully in registers; P C->A transform via per-wave LDS; no __syncthreads.
__global__ __launch_bounds__(256) void attn_mfma(
    const unsigned short* __restrict__ qb, const unsigned short* __restrict__ kb,
    const unsigned short* __restrict__ vT, float* __restrict__ out) {
  __shared__ unsigned short P[4][32][72];
  const int t = threadIdx.x;
  const int w = t >> 6;
  const int L = t & 63;
  const int c = L & 15;
  const int g = L >> 4;
  const int qt = blockIdx.x, hd = blockIdx.y, b = blockIdx.z;
  const size_t mrow0 = (size_t)b * S_ + qt * 128 + w * 32;
  const int dcol0 = hd * 64;

  short8v aq[2][2];
#pragma unroll
  for (int i = 0; i < 2; ++i)
#pragma unroll
    for (int st = 0; st < 2; ++st)
      aq[i][st] = *(const short8v*)(qb + (mrow0 + 16 * i + c) * D_ + dcol0 + 32 * st + 8 * g);

  float4v oacc[2][4];
  float m_run[2][4], l_run[2][4];
#pragma unroll
  for (int i = 0; i < 2; ++i)
#pragma unroll
    for (int r = 0; r < 4; ++r) { m_run[i][r] = -1e30f; l_run[i][r] = 0.f; }
#pragma unroll
  for (int i = 0; i < 2; ++i)
#pragma unroll
    for (int jv = 0; jv < 4; ++jv) oacc[i][jv] = (float4v){0.f, 0.f, 0.f, 0.f};

  const unsigned short* vbase = vT + (size_t)(b * NH_ + hd) * 64 * S_;
  const unsigned short* kbb = kb + (size_t)b * S_ * D_ + dcol0;

  for (int kt = 0; kt < 16; ++kt) {
    float4v sacc[2][4];
#pragma unroll
    for (int i = 0; i < 2; ++i)
#pragma unroll
      for (int j = 0; j < 4; ++j) sacc[i][j] = (float4v){0.f, 0.f, 0.f, 0.f};
#pragma unroll
    for (int j = 0; j < 4; ++j) {
      const unsigned short* kr = kbb + (size_t)(kt * 64 + 16 * j + c) * D_ + 8 * g;
      short8v bk0 = *(const short8v*)(kr);
      short8v bk1 = *(const short8v*)(kr + 32);
#pragma unroll
      for (int i = 0; i < 2; ++i) {
        sacc[i][j] = __builtin_amdgcn_mfma_f32_16x16x32_bf16(aq[i][0], bk0, sacc[i][j], 0, 0, 0);
        sacc[i][j] = __builtin_amdgcn_mfma_f32_16x16x32_bf16(aq[i][1], bk1, sacc[i][j], 0, 0, 0);
      }
    }
#pragma unroll
    for (int i = 0; i < 2; ++i)
#pragma unroll
      for (int r = 0; r < 4; ++r) {
        float mx = fmaxf(fmaxf(sacc[i][0][r], sacc[i][1][r]),
                         fmaxf(sacc[i][2][r], sacc[i][3][r]));
        mx = fmaxf(mx, __shfl_xor(mx, 1));
        mx = fmaxf(mx, __shfl_xor(mx, 2));
        mx = fmaxf(mx, __shfl_xor(mx, 4));
        mx = fmaxf(mx, __shfl_xor(mx, 8));
        float mn = fmaxf(m_run[i][r], mx);
        float al = __expf(m_run[i][r] - mn);
        m_run[i][r] = mn;
        float ps = 0.f;
#pragma unroll
        for (int j = 0; j < 4; ++j) {
          float p = __expf(sacc[i][j][r] - mn);
          ps += p;
          P[w][16 * i + 4 * g + r][16 * j + c] = f2bf(p);
        }
        l_run[i][r] = l_run[i][r] * al + ps;
#pragma unroll
        for (int jv = 0; jv < 4; ++jv) oacc[i][jv][r] *= al;
      }
    short8v ap[2][2];
#pragma unroll
    for (int i = 0; i < 2; ++i)
#pragma unroll
      for (int st = 0; st < 2; ++st) {
        const short4v* pp = (const short4v*)&P[w][16 * i + c][32 * st + 8 * g];
        short4v lo = pp[0];
        short4v hi = pp[1];
        short8v f;
        f[0] = lo[0]; f[1] = lo[1]; f[2] = lo[2]; f[3] = lo[3];
        f[4] = hi[0]; f[5] = hi[1]; f[6] = hi[2]; f[7] = hi[3];
        ap[i][st] = f;
      }
#pragma unroll
    for (int jv = 0; jv < 4; ++jv) {
      const unsigned short* vr = vbase + (size_t)(16 * jv + c) * S_ + kt * 64 + 8 * g;
      short8v bv0 = *(const short8v*)(vr);
      short8v bv1 = *(const short8v*)(vr + 32);
#pragma unroll
      for (int i = 0; i < 2; ++i) {
        oacc[i][jv] = __builtin_amdgcn_mfma_f32_16x16x32_bf16(ap[i][0], bv0, oacc[i][jv], 0, 0, 0);
        oacc[i][jv] = __builtin_amdgcn_mfma_f32_16x16x32_bf16(ap[i][1], bv1, oacc[i][jv], 0, 0, 0);
      }
    }
  }
#pragma unroll
  for (int i = 0; i < 2; ++i)
#pragma unroll
    for (int r = 0; r < 4; ++r) {
      float ls = l_run[i][r];
      ls += __shfl_xor(ls, 1);
      ls += __shfl_xor(ls, 2);
      ls += __shfl_xor(ls, 4);
      ls += __shfl_xor(ls, 8);
      float inv = 1.f / ls;
      size_t row = mrow0 + 16 * i + 4 * g + r;
#pragma unroll
      for (int jv = 0; jv < 4; ++jv)
        out[row * D_ + dcol0 + 16 * jv + c] = oacc[i][jv][r] * inv;
    }
}

// ---------------------------------------------------------------- launch
// Workspace layout (peak 192.03 MB — identical footprint to the passing round 1):
//   [0,32)MB qb bf16 | [32,64) kb bf16 | [64,96) vb bf16 | [96,128) vT bf16
//   [128,192) attn out fp32 | [192, +32KB) rope tables
extern "C" void kernel_launch(void* const* d_in, const int* in_sizes, int n_in,
                              void* d_out, int out_size, void* d_ws, size_t ws_size,
                              hipStream_t stream) {
  const float* x  = (const float*)d_in[0];
  const float* Wq = (const float*)d_in[1];
  const float* bq = (const float*)d_in[2];
  const float* Wk = (const float*)d_in[3];
  const float* bk = (const float*)d_in[4];
  const float* Wv = (const float*)d_in[5];
  const float* bv = (const float*)d_in[6];
  const float* Wo = (const float*)d_in[7];
  const float* bo = (const float*)d_in[8];
  float* out = (float*)d_out;

  char* ws = (char*)d_ws;
  const size_t SZ2 = (size_t)M_TOT * D_ * 2;   // 32 MB (bf16 plane)
  unsigned short* qb = (unsigned short*)(ws);
  unsigned short* kb = (unsigned short*)(ws + SZ2);
  unsigned short* vb = (unsigned short*)(ws + 2 * SZ2);
  unsigned short* vT = (unsigned short*)(ws + 3 * SZ2);
  float* attn_out    = (float*)(ws + 4 * SZ2);          // 64 MB
  float* cos1 = (float*)(ws + 6 * SZ2);                 // = ws + 192 MB (round-1-proven)
  float* sin1 = cos1 + S_ * 8;
  float* cos2 = sin1 + S_ * 8;
  float* sin2 = cos2 + 384;

  build_tables<<<34, 256, 0, stream>>>(cos1, sin1, cos2, sin2);

  dim3 ggrid(D_ / 128, M_TOT / 128);
  gemm_bias_bf16<<<ggrid, 256, 0, stream>>>(x, Wq, bq, qb);
  gemm_bias_bf16<<<ggrid, 256, 0, stream>>>(x, Wk, bk, kb);
  gemm_bias_bf16<<<ggrid, 256, 0, stream>>>(x, Wv, bv, vb);

  const int rope_blocks = (M_TOT * 512) / 256;   // 32768
  rope_inplace<<<rope_blocks, 256, 0, stream>>>(qb, cos1, sin1, cos2, sin2, 0.125f);
  rope_inplace<<<rope_blocks, 256, 0, stream>>>(kb, cos1, sin1, cos2, sin2, 1.0f);
  v_transpose<<<dim3(16, 16, 16), 256, 0, stream>>>(vb, vT);

  attn_mfma<<<dim3(8, NH_, B_), 256, 0, stream>>>(qb, kb, vT, attn_out);

  gemm_bias<<<ggrid, 256, 0, stream>>>(attn_out, Wo, bo, out);
}

// Round 4
// 697.285 us; speedup vs baseline: 4.1641x; 2.8953x over previous
//
#include <hip/hip_runtime.h>
#include <math.h>

#define B_ 16
#define S_ 1024
#define D_ 1024
#define NH_ 16
#define M_TOT (B_ * S_)

typedef __attribute__((ext_vector_type(8))) short short8v;
typedef __attribute__((ext_vector_type(4))) short short4v;
typedef __attribute__((ext_vector_type(4))) float float4v;

static __device__ __forceinline__ unsigned short f2bf(float f) {
  union { float f; unsigned u; } x; x.f = f;
  unsigned r = (x.u + 0x7fffu + ((x.u >> 16) & 1u)) >> 16;
  return (unsigned short)r;
}
static __device__ __forceinline__ float bf2f(unsigned short u) {
  union { unsigned u; float f; } x; x.u = ((unsigned)u) << 16;
  return x.f;
}

// async global->LDS, 16B per lane; LDS dest = wave-uniform base + lane*16 (m104)
static __device__ __forceinline__ void load_lds16(const unsigned short* g, unsigned short* l) {
  __builtin_amdgcn_global_load_lds(
      (const __attribute__((address_space(1))) unsigned int*)g,
      (__attribute__((address_space(3))) unsigned int*)l, 16, 0, 0);
}

// ---------------------------------------------------------------- RoPE tables
__global__ void build_tables(float* __restrict__ cos1, float* __restrict__ sin1,
                             float* __restrict__ cos2, float* __restrict__ sin2) {
  int t = blockIdx.x * 256 + threadIdx.x;
  if (t < S_ * 8) {
    int s = t >> 3, i = t & 7;
    double ang = (double)s * pow(10000.0, -(double)i / 8.0);
    cos1[t] = (float)cos(ang);
    sin1[t] = (float)sin(ang);
  } else if (t < S_ * 8 + 384) {
    int u = t - S_ * 8;
    int p = u / 12, j = u - p * 12;
    double ang = (double)p * pow(10000.0, -(double)j / 12.0);
    cos2[u] = (float)cos(ang);
    sin2[u] = (float)sin(ang);
  }
}

// ---------------------------------------------------------------- fp32 -> bf16
__global__ __launch_bounds__(256) void f32_to_bf16(
    const float* __restrict__ src, unsigned short* __restrict__ dst, int n4) {
  int i = blockIdx.x * 256 + threadIdx.x;
  if (i < n4) {
    float4 v = ((const float4*)src)[i];
    unsigned short t[4] = {f2bf(v.x), f2bf(v.y), f2bf(v.z), f2bf(v.w)};
    ((short4v*)dst)[i] = *(short4v*)t;
  }
}

// ---------------------------------------------------------------- bf16 MFMA GEMM
// C[M,1024] = A[M,1024] @ W[1024,1024]^T + bias.  m97 structure: 128x128 tile,
// BK=32, global_load_lds dwordx4 staging, 8 ds_read_b128 + 16 MFMA /wave/K-step.
template <bool BF16OUT>
__global__ __launch_bounds__(256) void gemm_mfma(
    const unsigned short* __restrict__ A, const unsigned short* __restrict__ W,
    const float* __restrict__ bias, void* __restrict__ Cout) {
  __shared__ unsigned short As[128 * 32];   // [row][k] contiguous, no pad (m104)
  __shared__ unsigned short Bs[128 * 32];
  const int t = threadIdx.x;
  const int w = t >> 6, L = t & 63;
  const int c = L & 15, g = L >> 4;
  const int bn = blockIdx.x * 128, bm = blockIdx.y * 128;

  // staging: wave w covers rows [w*32, w*32+32) of each tile, 2 issues of 16 rows
  const int srow = w * 32 + (L >> 2);
  const int sko = (L & 3) * 8;
  const unsigned short* gA = A + (size_t)(bm + srow) * D_ + sko;
  const unsigned short* gB = W + (size_t)(bn + srow) * D_ + sko;
  unsigned short* lA = As + w * 1024;   // wave-uniform; +lane*16B implicit
  unsigned short* lB = Bs + w * 1024;

  const int wm = (w >> 1) * 64, wn = (w & 1) * 64;

  float4v acc[4][4];
#pragma unroll
  for (int i = 0; i < 4; ++i)
#pragma unroll
    for (int j = 0; j < 4; ++j) acc[i][j] = (float4v){0.f, 0.f, 0.f, 0.f};

  for (int k0 = 0; k0 < D_; k0 += 32) {
    __syncthreads();   // prior compute done reading LDS
    load_lds16(gA + k0, lA);
    load_lds16(gA + k0 + 16 * D_, lA + 512);
    load_lds16(gB + k0, lB);
    load_lds16(gB + k0 + 16 * D_, lB + 512);
    __syncthreads();   // staged data visible (compiler drains vmcnt before barrier)
    short8v af[4], bf[4];
#pragma unroll
    for (int i = 0; i < 4; ++i)
      af[i] = *(const short8v*)&As[(wm + 16 * i + c) * 32 + 8 * g];
#pragma unroll
    for (int j = 0; j < 4; ++j)
      bf[j] = *(const short8v*)&Bs[(wn + 16 * j + c) * 32 + 8 * g];
#pragma unroll
    for (int i = 0; i < 4; ++i)
#pragma unroll
      for (int j = 0; j < 4; ++j)
        acc[i][j] = __builtin_amdgcn_mfma_f32_16x16x32_bf16(af[i], bf[j], acc[i][j], 0, 0, 0);
  }
  // epilogue: C/D layout col=lane&15, row=4g+r
#pragma unroll
  for (int i = 0; i < 4; ++i)
#pragma unroll
    for (int r = 0; r < 4; ++r) {
      const size_t row = (size_t)bm + wm + 16 * i + 4 * g + r;
#pragma unroll
      for (int j = 0; j < 4; ++j) {
        const int col = bn + wn + 16 * j + c;
        float vv = acc[i][j][r] + bias[col];
        if (BF16OUT)
          ((unsigned short*)Cout)[row * D_ + col] = f2bf(vv);
        else
          ((float*)Cout)[row * D_ + col] = vv;
      }
    }
}

// ---------------------------------------------------------------- RoPE in place (bf16)
__global__ __launch_bounds__(256) void rope_inplace(
    unsigned short* q,
    const float* __restrict__ cos1, const float* __restrict__ sin1,
    const float* __restrict__ cos2, const float* __restrict__ sin2,
    float scale) {
  int tid = blockIdx.x * 256 + threadIdx.x;
  int u = tid & 511;
  int m = tid >> 9;
  int s = m & (S_ - 1);
  int head = u >> 5, w = u & 31;
  size_t base = (size_t)m * D_ + head * 64;
  size_t c0, c1;
  float cv, sv;
  if (w < 8) {
    c0 = base + 2 * w; c1 = c0 + 1;
    cv = cos1[s * 8 + w]; sv = sin1[s * 8 + w];
  } else if (w < 20) {
    int j = w - 8, x = s & 31;
    c0 = base + 16 + j; c1 = base + 28 + j;
    cv = cos2[x * 12 + j]; sv = sin2[x * 12 + j];
  } else {
    int j = w - 20, y = s >> 5;
    c0 = base + 40 + j; c1 = base + 52 + j;
    cv = cos2[y * 12 + j]; sv = sin2[y * 12 + j];
  }
  float a = bf2f(q[c0]), b = bf2f(q[c1]);
  q[c0] = f2bf((a * cv - b * sv) * scale);
  q[c1] = f2bf((a * sv + b * cv) * scale);
}

// ---------------------------------------------------------------- V transpose (bf16)
// vb [b][s][head*64+n]  ->  vT [b][head][n(64)][s(1024)]
__global__ __launch_bounds__(256) void v_transpose(
    const unsigned short* __restrict__ v, unsigned short* __restrict__ vT) {
  __shared__ unsigned short T[64][72];
  const int t = threadIdx.x;
  const int st0 = blockIdx.x * 64;
  const int hd = blockIdx.y, b = blockIdx.z;
  const unsigned short* src = v + ((size_t)b * S_ + st0) * D_ + hd * 64;
#pragma unroll
  for (int rep = 0; rep < 4; ++rep) {
    int id = t + rep * 256;
    int s = id >> 4, n4 = (id & 15) * 4;
    short4v val = *(const short4v*)(src + (size_t)s * D_ + n4);
    T[n4 + 0][s] = val[0]; T[n4 + 1][s] = val[1];
    T[n4 + 2][s] = val[2]; T[n4 + 3][s] = val[3];
  }
  __syncthreads();
  unsigned short* dst = vT + ((size_t)(b * NH_ + hd) * 64) * S_ + st0;
#pragma unroll
  for (int rep = 0; rep < 2; ++rep) {
    int id = t + rep * 256;
    int n = id >> 3, s8 = (id & 7) * 8;
    unsigned short tmp[8];
#pragma unroll
    for (int u2 = 0; u2 < 8; ++u2) tmp[u2] = T[n][s8 + u2];
    *(short8v*)(dst + (size_t)n * S_ + s8) = *(short8v*)tmp;
  }
}

// ---------------------------------------------------------------- MFMA flash attention
// block = (qt, head, batch); 4 waves x 32 q-rows; register online softmax; bf16 out.
__global__ __launch_bounds__(256) void attn_mfma(
    const unsigned short* __restrict__ qb, const unsigned short* __restrict__ kb,
    const unsigned short* __restrict__ vT, unsigned short* __restrict__ out) {
  __shared__ unsigned short P[4][32][72];
  const int t = threadIdx.x;
  const int w = t >> 6;
  const int L = t & 63;
  const int c = L & 15;
  const int g = L >> 4;
  const int qt = blockIdx.x, hd = blockIdx.y, b = blockIdx.z;
  const size_t mrow0 = (size_t)b * S_ + qt * 128 + w * 32;
  const int dcol0 = hd * 64;

  short8v aq[2][2];
#pragma unroll
  for (int i = 0; i < 2; ++i)
#pragma unroll
    for (int st = 0; st < 2; ++st)
      aq[i][st] = *(const short8v*)(qb + (mrow0 + 16 * i + c) * D_ + dcol0 + 32 * st + 8 * g);

  float4v oacc[2][4];
  float m_run[2][4], l_run[2][4];
#pragma unroll
  for (int i = 0; i < 2; ++i)
#pragma unroll
    for (int r = 0; r < 4; ++r) { m_run[i][r] = -1e30f; l_run[i][r] = 0.f; }
#pragma unroll
  for (int i = 0; i < 2; ++i)
#pragma unroll
    for (int jv = 0; jv < 4; ++jv) oacc[i][jv] = (float4v){0.f, 0.f, 0.f, 0.f};

  const unsigned short* vbase = vT + (size_t)(b * NH_ + hd) * 64 * S_;
  const unsigned short* kbb = kb + (size_t)b * S_ * D_ + dcol0;

  for (int kt = 0; kt < 16; ++kt) {
    float4v sacc[2][4];
#pragma unroll
    for (int i = 0; i < 2; ++i)
#pragma unroll
      for (int j = 0; j < 4; ++j) sacc[i][j] = (float4v){0.f, 0.f, 0.f, 0.f};
#pragma unroll
    for (int j = 0; j < 4; ++j) {
      const unsigned short* kr = kbb + (size_t)(kt * 64 + 16 * j + c) * D_ + 8 * g;
      short8v bk0 = *(const short8v*)(kr);
      short8v bk1 = *(const short8v*)(kr + 32);
#pragma unroll
      for (int i = 0; i < 2; ++i) {
        sacc[i][j] = __builtin_amdgcn_mfma_f32_16x16x32_bf16(aq[i][0], bk0, sacc[i][j], 0, 0, 0);
        sacc[i][j] = __builtin_amdgcn_mfma_f32_16x16x32_bf16(aq[i][1], bk1, sacc[i][j], 0, 0, 0);
      }
    }
#pragma unroll
    for (int i = 0; i < 2; ++i)
#pragma unroll
      for (int r = 0; r < 4; ++r) {
        float mx = fmaxf(fmaxf(sacc[i][0][r], sacc[i][1][r]),
                         fmaxf(sacc[i][2][r], sacc[i][3][r]));
        mx = fmaxf(mx, __shfl_xor(mx, 1));
        mx = fmaxf(mx, __shfl_xor(mx, 2));
        mx = fmaxf(mx, __shfl_xor(mx, 4));
        mx = fmaxf(mx, __shfl_xor(mx, 8));
        float mn = fmaxf(m_run[i][r], mx);
        float al = __expf(m_run[i][r] - mn);
        m_run[i][r] = mn;
        float ps = 0.f;
#pragma unroll
        for (int j = 0; j < 4; ++j) {
          float p = __expf(sacc[i][j][r] - mn);
          ps += p;
          P[w][16 * i + 4 * g + r][16 * j + c] = f2bf(p);
        }
        l_run[i][r] = l_run[i][r] * al + ps;
#pragma unroll
        for (int jv = 0; jv < 4; ++jv) oacc[i][jv][r] *= al;
      }
    short8v ap[2][2];
#pragma unroll
    for (int i = 0; i < 2; ++i)
#pragma unroll
      for (int st = 0; st < 2; ++st) {
        const short4v* pp = (const short4v*)&P[w][16 * i + c][32 * st + 8 * g];
        short4v lo = pp[0];
        short4v hi = pp[1];
        short8v f;
        f[0] = lo[0]; f[1] = lo[1]; f[2] = lo[2]; f[3] = lo[3];
        f[4] = hi[0]; f[5] = hi[1]; f[6] = hi[2]; f[7] = hi[3];
        ap[i][st] = f;
      }
#pragma unroll
    for (int jv = 0; jv < 4; ++jv) {
      const unsigned short* vr = vbase + (size_t)(16 * jv + c) * S_ + kt * 64 + 8 * g;
      short8v bv0 = *(const short8v*)(vr);
      short8v bv1 = *(const short8v*)(vr + 32);
#pragma unroll
      for (int i = 0; i < 2; ++i) {
        oacc[i][jv] = __builtin_amdgcn_mfma_f32_16x16x32_bf16(ap[i][0], bv0, oacc[i][jv], 0, 0, 0);
        oacc[i][jv] = __builtin_amdgcn_mfma_f32_16x16x32_bf16(ap[i][1], bv1, oacc[i][jv], 0, 0, 0);
      }
    }
  }
#pragma unroll
  for (int i = 0; i < 2; ++i)
#pragma unroll
    for (int r = 0; r < 4; ++r) {
      float ls = l_run[i][r];
      ls += __shfl_xor(ls, 1);
      ls += __shfl_xor(ls, 2);
      ls += __shfl_xor(ls, 4);
      ls += __shfl_xor(ls, 8);
      float inv = 1.f / ls;
      size_t row = mrow0 + 16 * i + 4 * g + r;
#pragma unroll
      for (int jv = 0; jv < 4; ++jv)
        out[row * D_ + dcol0 + 16 * jv + c] = f2bf(oacc[i][jv][r] * inv);
    }
}

// ---------------------------------------------------------------- launch
// Workspace (peak 168.03 MB < 192 MB proven):
//   [0,32)MB xb (reused as ob after QKV gemms) | [32,64) qb | [64,96) kb
//   [96,128) vb | [128,160) vT | [160,168) wqb,wkb,wvb,wob | [168,+32KB) tables
extern "C" void kernel_launch(void* const* d_in, const int* in_sizes, int n_in,
                              void* d_out, int out_size, void* d_ws, size_t ws_size,
                              hipStream_t stream) {
  const float* x  = (const float*)d_in[0];
  const float* Wq = (const float*)d_in[1];
  const float* bq = (const float*)d_in[2];
  const float* Wk = (const float*)d_in[3];
  const float* bk = (const float*)d_in[4];
  const float* Wv = (const float*)d_in[5];
  const float* bv = (const float*)d_in[6];
  const float* Wo = (const float*)d_in[7];
  const float* bo = (const float*)d_in[8];
  float* out = (float*)d_out;

  char* ws = (char*)d_ws;
  const size_t SZ2 = (size_t)M_TOT * D_ * 2;   // 32 MB
  unsigned short* xb = (unsigned short*)(ws);
  unsigned short* ob = xb;                               // alias: free after QKV gemms
  unsigned short* qb = (unsigned short*)(ws + SZ2);
  unsigned short* kb = (unsigned short*)(ws + 2 * SZ2);
  unsigned short* vb = (unsigned short*)(ws + 3 * SZ2);
  unsigned short* vT = (unsigned short*)(ws + 4 * SZ2);
  unsigned short* wqb = (unsigned short*)(ws + 5 * SZ2);
  unsigned short* wkb = wqb + (size_t)D_ * D_;
  unsigned short* wvb = wkb + (size_t)D_ * D_;
  unsigned short* wob = wvb + (size_t)D_ * D_;
  float* cos1 = (float*)(ws + 5 * SZ2 + 4 * (size_t)D_ * D_ * 2);
  float* sin1 = cos1 + S_ * 8;
  float* cos2 = sin1 + S_ * 8;
  float* sin2 = cos2 + 384;

  build_tables<<<34, 256, 0, stream>>>(cos1, sin1, cos2, sin2);

  f32_to_bf16<<<M_TOT * D_ / 4 / 256, 256, 0, stream>>>(x, xb, M_TOT * D_ / 4);
  f32_to_bf16<<<D_ * D_ / 4 / 256, 256, 0, stream>>>(Wq, wqb, D_ * D_ / 4);
  f32_to_bf16<<<D_ * D_ / 4 / 256, 256, 0, stream>>>(Wk, wkb, D_ * D_ / 4);
  f32_to_bf16<<<D_ * D_ / 4 / 256, 256, 0, stream>>>(Wv, wvb, D_ * D_ / 4);
  f32_to_bf16<<<D_ * D_ / 4 / 256, 256, 0, stream>>>(Wo, wob, D_ * D_ / 4);

  dim3 ggrid(D_ / 128, M_TOT / 128);
  gemm_mfma<true><<<ggrid, 256, 0, stream>>>(xb, wqb, bq, qb);
  gemm_mfma<true><<<ggrid, 256, 0, stream>>>(xb, wkb, bk, kb);
  gemm_mfma<true><<<ggrid, 256, 0, stream>>>(xb, wvb, bv, vb);

  const int rope_blocks = (M_TOT * 512) / 256;
  rope_inplace<<<rope_blocks, 256, 0, stream>>>(qb, cos1, sin1, cos2, sin2, 0.125f);
  rope_inplace<<<rope_blocks, 256, 0, stream>>>(kb, cos1, sin1, cos2, sin2, 1.0f);
  v_transpose<<<dim3(16, 16, 16), 256, 0, stream>>>(vb, vT);

  attn_mfma<<<dim3(8, NH_, B_), 256, 0, stream>>>(qb, kb, vT, ob);

  gemm_mfma<false><<<ggrid, 256, 0, stream>>>(ob, wob, bo, out);
}

// Round 5
// 619.124 us; speedup vs baseline: 4.6898x; 1.1262x over previous
//
#include <hip/hip_runtime.h>
#include <math.h>

#define B_ 16
#define S_ 1024
#define D_ 1024
#define NH_ 16
#define M_TOT (B_ * S_)

typedef __attribute__((ext_vector_type(8))) short short8v;
typedef __attribute__((ext_vector_type(4))) short short4v;
typedef __attribute__((ext_vector_type(4))) float float4v;

static __device__ __forceinline__ unsigned short f2bf(float f) {
  union { float f; unsigned u; } x; x.f = f;
  unsigned r = (x.u + 0x7fffu + ((x.u >> 16) & 1u)) >> 16;
  return (unsigned short)r;
}
static __device__ __forceinline__ float bf2f(unsigned short u) {
  union { unsigned u; float f; } x; x.u = ((unsigned)u) << 16;
  return x.f;
}

// async global->LDS, 16B per lane; LDS dest = wave-uniform base + lane*16 (m104)
static __device__ __forceinline__ void load_lds16(const unsigned short* g, unsigned short* l) {
  __builtin_amdgcn_global_load_lds(
      (const __attribute__((address_space(1))) unsigned int*)g,
      (__attribute__((address_space(3))) unsigned int*)l, 16, 0, 0);
}

// ---------------------------------------------------------------- RoPE tables
__global__ void build_tables(float* __restrict__ cos1, float* __restrict__ sin1,
                             float* __restrict__ cos2, float* __restrict__ sin2) {
  int t = blockIdx.x * 256 + threadIdx.x;
  if (t < S_ * 8) {
    int s = t >> 3, i = t & 7;
    double ang = (double)s * pow(10000.0, -(double)i / 8.0);
    cos1[t] = (float)cos(ang);
    sin1[t] = (float)sin(ang);
  } else if (t < S_ * 8 + 384) {
    int u = t - S_ * 8;
    int p = u / 12, j = u - p * 12;
    double ang = (double)p * pow(10000.0, -(double)j / 12.0);
    cos2[u] = (float)cos(ang);
    sin2[u] = (float)sin(ang);
  }
}

// ---------------------------------------------------------------- fp32 -> bf16
__global__ __launch_bounds__(256) void f32_to_bf16(
    const float* __restrict__ src, unsigned short* __restrict__ dst, int n4) {
  int i = blockIdx.x * 256 + threadIdx.x;
  if (i < n4) {
    float4 v = ((const float4*)src)[i];
    unsigned short t[4] = {f2bf(v.x), f2bf(v.y), f2bf(v.z), f2bf(v.w)};
    ((short4v*)dst)[i] = *(short4v*)t;
  }
}

// ---------------------------------------------------------------- bf16 MFMA GEMM
// C[M,1024] = A[M,1024] @ W[1024,1024]^T + bias.  m97 structure: 128x128 tile,
// BK=32, global_load_lds dwordx4 staging, 8 ds_read_b128 + 16 MFMA /wave/K-step.
// Grid: x = bm (128, fastest) so the 8 blocks sharing an A-tile are 128 apart
// in linear id -> same XCD (id%8 equal) -> A stays L2-resident.
template <bool BF16OUT>
__global__ __launch_bounds__(256) void gemm_mfma(
    const unsigned short* __restrict__ A, const unsigned short* __restrict__ W,
    const float* __restrict__ bias, void* __restrict__ Cout) {
  __shared__ unsigned short As[128 * 32];   // [row][k] contiguous, no pad (m104)
  __shared__ unsigned short Bs[128 * 32];
  const int t = threadIdx.x;
  const int w = t >> 6, L = t & 63;
  const int c = L & 15, g = L >> 4;
  const int bm = blockIdx.x * 128, bn = blockIdx.y * 128;

  const int srow = w * 32 + (L >> 2);
  const int sko = (L & 3) * 8;
  const unsigned short* gA = A + (size_t)(bm + srow) * D_ + sko;
  const unsigned short* gB = W + (size_t)(bn + srow) * D_ + sko;
  unsigned short* lA = As + w * 1024;
  unsigned short* lB = Bs + w * 1024;

  const int wm = (w >> 1) * 64, wn = (w & 1) * 64;

  float4v acc[4][4];
#pragma unroll
  for (int i = 0; i < 4; ++i)
#pragma unroll
    for (int j = 0; j < 4; ++j) acc[i][j] = (float4v){0.f, 0.f, 0.f, 0.f};

  for (int k0 = 0; k0 < D_; k0 += 32) {
    __syncthreads();
    load_lds16(gA + k0, lA);
    load_lds16(gA + k0 + 16 * D_, lA + 512);
    load_lds16(gB + k0, lB);
    load_lds16(gB + k0 + 16 * D_, lB + 512);
    __syncthreads();
    short8v af[4], bf[4];
#pragma unroll
    for (int i = 0; i < 4; ++i)
      af[i] = *(const short8v*)&As[(wm + 16 * i + c) * 32 + 8 * g];
#pragma unroll
    for (int j = 0; j < 4; ++j)
      bf[j] = *(const short8v*)&Bs[(wn + 16 * j + c) * 32 + 8 * g];
#pragma unroll
    for (int i = 0; i < 4; ++i)
#pragma unroll
      for (int j = 0; j < 4; ++j)
        acc[i][j] = __builtin_amdgcn_mfma_f32_16x16x32_bf16(af[i], bf[j], acc[i][j], 0, 0, 0);
  }
#pragma unroll
  for (int i = 0; i < 4; ++i)
#pragma unroll
    for (int r = 0; r < 4; ++r) {
      const size_t row = (size_t)bm + wm + 16 * i + 4 * g + r;
#pragma unroll
      for (int j = 0; j < 4; ++j) {
        const int col = bn + wn + 16 * j + c;
        float vv = acc[i][j][r] + bias[col];
        if (BF16OUT)
          ((unsigned short*)Cout)[row * D_ + col] = f2bf(vv);
        else
          ((float*)Cout)[row * D_ + col] = vv;
      }
    }
}

// ---------------------------------------------------------------- RoPE in place (bf16)
__global__ __launch_bounds__(256) void rope_inplace(
    unsigned short* q,
    const float* __restrict__ cos1, const float* __restrict__ sin1,
    const float* __restrict__ cos2, const float* __restrict__ sin2,
    float scale) {
  int tid = blockIdx.x * 256 + threadIdx.x;
  int u = tid & 511;
  int m = tid >> 9;
  int s = m & (S_ - 1);
  int head = u >> 5, w = u & 31;
  size_t base = (size_t)m * D_ + head * 64;
  size_t c0, c1;
  float cv, sv;
  if (w < 8) {
    c0 = base + 2 * w; c1 = c0 + 1;
    cv = cos1[s * 8 + w]; sv = sin1[s * 8 + w];
  } else if (w < 20) {
    int j = w - 8, x = s & 31;
    c0 = base + 16 + j; c1 = base + 28 + j;
    cv = cos2[x * 12 + j]; sv = sin2[x * 12 + j];
  } else {
    int j = w - 20, y = s >> 5;
    c0 = base + 40 + j; c1 = base + 52 + j;
    cv = cos2[y * 12 + j]; sv = sin2[y * 12 + j];
  }
  float a = bf2f(q[c0]), b = bf2f(q[c1]);
  q[c0] = f2bf((a * cv - b * sv) * scale);
  q[c1] = f2bf((a * sv + b * cv) * scale);
}

// ---------------------------------------------------------------- V transpose (bf16)
// vb [b][s][head*64+n]  ->  vT [b][head][n(64)][s(1024)]
__global__ __launch_bounds__(256) void v_transpose(
    const unsigned short* __restrict__ v, unsigned short* __restrict__ vT) {
  __shared__ unsigned short T[64][72];
  const int t = threadIdx.x;
  const int st0 = blockIdx.x * 64;
  const int hd = blockIdx.y, b = blockIdx.z;
  const unsigned short* src = v + ((size_t)b * S_ + st0) * D_ + hd * 64;
#pragma unroll
  for (int rep = 0; rep < 4; ++rep) {
    int id = t + rep * 256;
    int s = id >> 4, n4 = (id & 15) * 4;
    short4v val = *(const short4v*)(src + (size_t)s * D_ + n4);
    T[n4 + 0][s] = val[0]; T[n4 + 1][s] = val[1];
    T[n4 + 2][s] = val[2]; T[n4 + 3][s] = val[3];
  }
  __syncthreads();
  unsigned short* dst = vT + ((size_t)(b * NH_ + hd) * 64) * S_ + st0;
#pragma unroll
  for (int rep = 0; rep < 2; ++rep) {
    int id = t + rep * 256;
    int n = id >> 3, s8 = (id & 7) * 8;
    unsigned short tmp[8];
#pragma unroll
    for (int u2 = 0; u2 < 8; ++u2) tmp[u2] = T[n][s8 + u2];
    *(short8v*)(dst + (size_t)n * S_ + s8) = *(short8v*)tmp;
  }
}

// ---------------------------------------------------------------- MFMA flash attention
// grid = (pair=b*16+hd, qt): all 8 qt blocks of a pair are 256 apart in linear
// id -> same XCD -> K/V (256 KB/pair) L2-resident.
// No-max softmax: logits bounded (|s| <~ 6, hard CS bound), exp cannot overflow;
// removes the shfl max-reduce + alpha rescale from the critical path.
// K double-buffered in registers (prefetch kt+1 before QK); V issued before QK.
__global__ __launch_bounds__(256) void attn_mfma(
    const unsigned short* __restrict__ qb, const unsigned short* __restrict__ kb,
    const unsigned short* __restrict__ vT, unsigned short* __restrict__ out) {
  __shared__ unsigned short P[4][32][72];
  const int t = threadIdx.x;
  const int w = t >> 6;
  const int L = t & 63;
  const int c = L & 15;
  const int g = L >> 4;
  const int pid = blockIdx.x;
  const int b = pid >> 4, hd = pid & 15;
  const int qt = blockIdx.y;
  const size_t mrow0 = (size_t)b * S_ + qt * 128 + w * 32;
  const int dcol0 = hd * 64;

  short8v aq[2][2];
#pragma unroll
  for (int i = 0; i < 2; ++i)
#pragma unroll
    for (int st = 0; st < 2; ++st)
      aq[i][st] = *(const short8v*)(qb + (mrow0 + 16 * i + c) * D_ + dcol0 + 32 * st + 8 * g);

  float4v oacc[2][4];
  float l_run[2][4];
#pragma unroll
  for (int i = 0; i < 2; ++i)
#pragma unroll
    for (int r = 0; r < 4; ++r) l_run[i][r] = 0.f;
#pragma unroll
  for (int i = 0; i < 2; ++i)
#pragma unroll
    for (int jv = 0; jv < 4; ++jv) oacc[i][jv] = (float4v){0.f, 0.f, 0.f, 0.f};

  const unsigned short* vbase = vT + (size_t)(b * NH_ + hd) * 64 * S_;
  const unsigned short* kbb = kb + (size_t)b * S_ * D_ + dcol0;

  short8v kf[2][4][2];
#pragma unroll
  for (int j = 0; j < 4; ++j) {
    const unsigned short* kr = kbb + (size_t)(16 * j + c) * D_ + 8 * g;
    kf[0][j][0] = *(const short8v*)(kr);
    kf[0][j][1] = *(const short8v*)(kr + 32);
  }

#pragma unroll 2
  for (int kt = 0; kt < 16; ++kt) {
    const int cur = kt & 1;
    // prefetch next K tile into the other register buffer (lands during softmax/PV)
    if (kt < 15) {
#pragma unroll
      for (int j = 0; j < 4; ++j) {
        const unsigned short* kr = kbb + (size_t)((kt + 1) * 64 + 16 * j + c) * D_ + 8 * g;
        kf[cur ^ 1][j][0] = *(const short8v*)(kr);
        kf[cur ^ 1][j][1] = *(const short8v*)(kr + 32);
      }
    }
    // V for this tile, issued before QK (consumed only after softmax)
    short8v vf[4][2];
#pragma unroll
    for (int jv = 0; jv < 4; ++jv) {
      const unsigned short* vr = vbase + (size_t)(16 * jv + c) * S_ + kt * 64 + 8 * g;
      vf[jv][0] = *(const short8v*)(vr);
      vf[jv][1] = *(const short8v*)(vr + 32);
    }
    // ---- QK (kf[cur] already in registers: no wait)
    float4v sacc[2][4];
#pragma unroll
    for (int i = 0; i < 2; ++i)
#pragma unroll
      for (int j = 0; j < 4; ++j) sacc[i][j] = (float4v){0.f, 0.f, 0.f, 0.f};
#pragma unroll
    for (int j = 0; j < 4; ++j)
#pragma unroll
      for (int i = 0; i < 2; ++i) {
        sacc[i][j] = __builtin_amdgcn_mfma_f32_16x16x32_bf16(aq[i][0], kf[cur][j][0], sacc[i][j], 0, 0, 0);
        sacc[i][j] = __builtin_amdgcn_mfma_f32_16x16x32_bf16(aq[i][1], kf[cur][j][1], sacc[i][j], 0, 0, 0);
      }
    // ---- softmax, no max subtraction; write P bf16 to per-wave LDS
#pragma unroll
    for (int i = 0; i < 2; ++i)
#pragma unroll
      for (int r = 0; r < 4; ++r) {
        float ps = 0.f;
#pragma unroll
        for (int j = 0; j < 4; ++j) {
          float p = __expf(sacc[i][j][r]);
          ps += p;
          P[w][16 * i + 4 * g + r][16 * j + c] = f2bf(p);
        }
        l_run[i][r] += ps;
      }
    // ---- P back as A-frags
    short8v ap[2][2];
#pragma unroll
    for (int i = 0; i < 2; ++i)
#pragma unroll
      for (int st = 0; st < 2; ++st) {
        const short4v* pp = (const short4v*)&P[w][16 * i + c][32 * st + 8 * g];
        short4v lo = pp[0];
        short4v hi = pp[1];
        short8v f;
        f[0] = lo[0]; f[1] = lo[1]; f[2] = lo[2]; f[3] = lo[3];
        f[4] = hi[0]; f[5] = hi[1]; f[6] = hi[2]; f[7] = hi[3];
        ap[i][st] = f;
      }
    // ---- O += P V
#pragma unroll
    for (int jv = 0; jv < 4; ++jv)
#pragma unroll
      for (int i = 0; i < 2; ++i) {
        oacc[i][jv] = __builtin_amdgcn_mfma_f32_16x16x32_bf16(ap[i][0], vf[jv][0], oacc[i][jv], 0, 0, 0);
        oacc[i][jv] = __builtin_amdgcn_mfma_f32_16x16x32_bf16(ap[i][1], vf[jv][1], oacc[i][jv], 0, 0, 0);
      }
  }
  // ---- epilogue: reduce l across the 16-lane row groups, normalize, store bf16
#pragma unroll
  for (int i = 0; i < 2; ++i)
#pragma unroll
    for (int r = 0; r < 4; ++r) {
      float ls = l_run[i][r];
      ls += __shfl_xor(ls, 1);
      ls += __shfl_xor(ls, 2);
      ls += __shfl_xor(ls, 4);
      ls += __shfl_xor(ls, 8);
      float inv = 1.f / ls;
      size_t row = mrow0 + 16 * i + 4 * g + r;
#pragma unroll
      for (int jv = 0; jv < 4; ++jv)
        out[row * D_ + dcol0 + 16 * jv + c] = f2bf(oacc[i][jv][r] * inv);
    }
}

// ---------------------------------------------------------------- launch
// Workspace (peak 168.03 MB < 192 MB proven):
//   [0,32)MB xb (reused as ob after QKV gemms) | [32,64) qb | [64,96) kb
//   [96,128) vb | [128,160) vT | [160,168) wqb,wkb,wvb,wob | [168,+32KB) tables
extern "C" void kernel_launch(void* const* d_in, const int* in_sizes, int n_in,
                              void* d_out, int out_size, void* d_ws, size_t ws_size,
                              hipStream_t stream) {
  const float* x  = (const float*)d_in[0];
  const float* Wq = (const float*)d_in[1];
  const float* bq = (const float*)d_in[2];
  const float* Wk = (const float*)d_in[3];
  const float* bk = (const float*)d_in[4];
  const float* Wv = (const float*)d_in[5];
  const float* bv = (const float*)d_in[6];
  const float* Wo = (const float*)d_in[7];
  const float* bo = (const float*)d_in[8];
  float* out = (float*)d_out;

  char* ws = (char*)d_ws;
  const size_t SZ2 = (size_t)M_TOT * D_ * 2;   // 32 MB
  unsigned short* xb = (unsigned short*)(ws);
  unsigned short* ob = xb;                               // alias: free after QKV gemms
  unsigned short* qb = (unsigned short*)(ws + SZ2);
  unsigned short* kb = (unsigned short*)(ws + 2 * SZ2);
  unsigned short* vb = (unsigned short*)(ws + 3 * SZ2);
  unsigned short* vT = (unsigned short*)(ws + 4 * SZ2);
  unsigned short* wqb = (unsigned short*)(ws + 5 * SZ2);
  unsigned short* wkb = wqb + (size_t)D_ * D_;
  unsigned short* wvb = wkb + (size_t)D_ * D_;
  unsigned short* wob = wvb + (size_t)D_ * D_;
  float* cos1 = (float*)(ws + 5 * SZ2 + 4 * (size_t)D_ * D_ * 2);
  float* sin1 = cos1 + S_ * 8;
  float* cos2 = sin1 + S_ * 8;
  float* sin2 = cos2 + 384;

  build_tables<<<34, 256, 0, stream>>>(cos1, sin1, cos2, sin2);

  f32_to_bf16<<<M_TOT * D_ / 4 / 256, 256, 0, stream>>>(x, xb, M_TOT * D_ / 4);
  f32_to_bf16<<<D_ * D_ / 4 / 256, 256, 0, stream>>>(Wq, wqb, D_ * D_ / 4);
  f32_to_bf16<<<D_ * D_ / 4 / 256, 256, 0, stream>>>(Wk, wkb, D_ * D_ / 4);
  f32_to_bf16<<<D_ * D_ / 4 / 256, 256, 0, stream>>>(Wv, wvb, D_ * D_ / 4);
  f32_to_bf16<<<D_ * D_ / 4 / 256, 256, 0, stream>>>(Wo, wob, D_ * D_ / 4);

  dim3 ggrid(M_TOT / 128, D_ / 128);   // x = bm (A-tile sharers land on one XCD)
  gemm_mfma<true><<<ggrid, 256, 0, stream>>>(xb, wqb, bq, qb);
  gemm_mfma<true><<<ggrid, 256, 0, stream>>>(xb, wkb, bk, kb);
  gemm_mfma<true><<<ggrid, 256, 0, stream>>>(xb, wvb, bv, vb);

  const int rope_blocks = (M_TOT * 512) / 256;
  rope_inplace<<<rope_blocks, 256, 0, stream>>>(qb, cos1, sin1, cos2, sin2, 0.125f);
  rope_inplace<<<rope_blocks, 256, 0, stream>>>(kb, cos1, sin1, cos2, sin2, 1.0f);
  v_transpose<<<dim3(16, 16, 16), 256, 0, stream>>>(vb, vT);

  attn_mfma<<<dim3(NH_ * B_, 8), 256, 0, stream>>>(qb, kb, vT, ob);

  gemm_mfma<false><<<ggrid, 256, 0, stream>>>(ob, wob, bo, out);
}

// Round 6
// 612.608 us; speedup vs baseline: 4.7397x; 1.0106x over previous
//
#include <hip/hip_runtime.h>
#include <math.h>

#define B_ 16
#define S_ 1024
#define D_ 1024
#define NH_ 16
#define M_TOT (B_ * S_)

typedef __attribute__((ext_vector_type(8))) short short8v;
typedef __attribute__((ext_vector_type(4))) short short4v;
typedef __attribute__((ext_vector_type(4))) float float4v;

static __device__ __forceinline__ unsigned short f2bf(float f) {
  union { float f; unsigned u; } x; x.f = f;
  unsigned r = (x.u + 0x7fffu + ((x.u >> 16) & 1u)) >> 16;
  return (unsigned short)r;
}
static __device__ __forceinline__ float bf2f(unsigned short u) {
  union { unsigned u; float f; } x; x.u = ((unsigned)u) << 16;
  return x.f;
}

// async global->LDS, 16B per lane; LDS dest = wave-uniform base + lane*16 (m104)
static __device__ __forceinline__ void load_lds16(const unsigned short* g, unsigned short* l) {
  __builtin_amdgcn_global_load_lds(
      (const __attribute__((address_space(1))) unsigned int*)g,
      (__attribute__((address_space(3))) unsigned int*)l, 16, 0, 0);
}

// ---------------------------------------------------------------- RoPE tables
__global__ void build_tables(float* __restrict__ cos1, float* __restrict__ sin1,
                             float* __restrict__ cos2, float* __restrict__ sin2) {
  int t = blockIdx.x * 256 + threadIdx.x;
  if (t < S_ * 8) {
    int s = t >> 3, i = t & 7;
    double ang = (double)s * pow(10000.0, -(double)i / 8.0);
    cos1[t] = (float)cos(ang);
    sin1[t] = (float)sin(ang);
  } else if (t < S_ * 8 + 384) {
    int u = t - S_ * 8;
    int p = u / 12, j = u - p * 12;
    double ang = (double)p * pow(10000.0, -(double)j / 12.0);
    cos2[u] = (float)cos(ang);
    sin2[u] = (float)sin(ang);
  }
}

// ---------------------------------------------------------------- fp32 -> bf16
__global__ __launch_bounds__(256) void f32_to_bf16(
    const float* __restrict__ src, unsigned short* __restrict__ dst, int n4) {
  int i = blockIdx.x * 256 + threadIdx.x;
  if (i < n4) {
    float4 v = ((const float4*)src)[i];
    unsigned short t[4] = {f2bf(v.x), f2bf(v.y), f2bf(v.z), f2bf(v.w)};
    ((short4v*)dst)[i] = *(short4v*)t;
  }
}

// all four 1024x1024 weights in one launch (blockIdx.y selects the matrix)
__global__ __launch_bounds__(256) void w4_to_bf16(
    const float* __restrict__ w0, const float* __restrict__ w1,
    const float* __restrict__ w2, const float* __restrict__ w3,
    unsigned short* __restrict__ dst) {
  const float* srcs[4] = {w0, w1, w2, w3};
  const float* src = srcs[blockIdx.y];
  unsigned short* d = dst + (size_t)blockIdx.y * D_ * D_;
  int i = blockIdx.x * 256 + threadIdx.x;   // < D_*D_/4
  float4 v = ((const float4*)src)[i];
  unsigned short t[4] = {f2bf(v.x), f2bf(v.y), f2bf(v.z), f2bf(v.w)};
  ((short4v*)d)[i] = *(short4v*)t;
}

// ---------------------------------------------------------------- bf16 MFMA GEMM
// C[M,1024] = A[M,1024] @ W[1024,1024]^T + bias.  m97 structure: 128x128 tile,
// BK=32, global_load_lds dwordx4 staging, 8 ds_read_b128 + 16 MFMA /wave/K-step.
// Grid: 1024 linear, swizzled so the 8 bn-blocks sharing an A-tile are within
// 64 CONSECUTIVE ids on ONE XCD (id%8) -> temporal+spatial L2 co-residency.
template <bool BF16OUT>
__global__ __launch_bounds__(256) void gemm_mfma(
    const unsigned short* __restrict__ A, const unsigned short* __restrict__ W,
    const float* __restrict__ bias, void* __restrict__ Cout) {
  __shared__ unsigned short As[128 * 32];   // [row][k] contiguous, no pad (m104)
  __shared__ unsigned short Bs[128 * 32];
  const int t = threadIdx.x;
  const int w = t >> 6, L = t & 63;
  const int c = L & 15, g = L >> 4;
  const int id = blockIdx.x;
  const int xcd = id & 7, slot = id >> 3;
  const int bn = (slot & 7) * 128;
  const int bm = ((slot >> 3) * 8 + xcd) * 128;

  const int srow = w * 32 + (L >> 2);
  const int sko = (L & 3) * 8;
  const unsigned short* gA = A + (size_t)(bm + srow) * D_ + sko;
  const unsigned short* gB = W + (size_t)(bn + srow) * D_ + sko;
  unsigned short* lA = As + w * 1024;
  unsigned short* lB = Bs + w * 1024;

  const int wm = (w >> 1) * 64, wn = (w & 1) * 64;

  float4v acc[4][4];
#pragma unroll
  for (int i = 0; i < 4; ++i)
#pragma unroll
    for (int j = 0; j < 4; ++j) acc[i][j] = (float4v){0.f, 0.f, 0.f, 0.f};

  for (int k0 = 0; k0 < D_; k0 += 32) {
    __syncthreads();
    load_lds16(gA + k0, lA);
    load_lds16(gA + k0 + 16 * D_, lA + 512);
    load_lds16(gB + k0, lB);
    load_lds16(gB + k0 + 16 * D_, lB + 512);
    __syncthreads();
    short8v af[4], bf[4];
#pragma unroll
    for (int i = 0; i < 4; ++i)
      af[i] = *(const short8v*)&As[(wm + 16 * i + c) * 32 + 8 * g];
#pragma unroll
    for (int j = 0; j < 4; ++j)
      bf[j] = *(const short8v*)&Bs[(wn + 16 * j + c) * 32 + 8 * g];
#pragma unroll
    for (int i = 0; i < 4; ++i)
#pragma unroll
      for (int j = 0; j < 4; ++j)
        acc[i][j] = __builtin_amdgcn_mfma_f32_16x16x32_bf16(af[i], bf[j], acc[i][j], 0, 0, 0);
  }
#pragma unroll
  for (int i = 0; i < 4; ++i)
#pragma unroll
    for (int r = 0; r < 4; ++r) {
      const size_t row = (size_t)bm + wm + 16 * i + 4 * g + r;
#pragma unroll
      for (int j = 0; j < 4; ++j) {
        const int col = bn + wn + 16 * j + c;
        float vv = acc[i][j][r] + bias[col];
        if (BF16OUT)
          ((unsigned short*)Cout)[row * D_ + col] = f2bf(vv);
        else
          ((float*)Cout)[row * D_ + col] = vv;
      }
    }
}

// ---------------------------------------------------------------- RoPE in place (bf16)
__global__ __launch_bounds__(256) void rope_inplace(
    unsigned short* q,
    const float* __restrict__ cos1, const float* __restrict__ sin1,
    const float* __restrict__ cos2, const float* __restrict__ sin2,
    float scale) {
  int tid = blockIdx.x * 256 + threadIdx.x;
  int u = tid & 511;
  int m = tid >> 9;
  int s = m & (S_ - 1);
  int head = u >> 5, w = u & 31;
  size_t base = (size_t)m * D_ + head * 64;
  size_t c0, c1;
  float cv, sv;
  if (w < 8) {
    c0 = base + 2 * w; c1 = c0 + 1;
    cv = cos1[s * 8 + w]; sv = sin1[s * 8 + w];
  } else if (w < 20) {
    int j = w - 8, x = s & 31;
    c0 = base + 16 + j; c1 = base + 28 + j;
    cv = cos2[x * 12 + j]; sv = sin2[x * 12 + j];
  } else {
    int j = w - 20, y = s >> 5;
    c0 = base + 40 + j; c1 = base + 52 + j;
    cv = cos2[y * 12 + j]; sv = sin2[y * 12 + j];
  }
  float a = bf2f(q[c0]), b = bf2f(q[c1]);
  q[c0] = f2bf((a * cv - b * sv) * scale);
  q[c1] = f2bf((a * sv + b * cv) * scale);
}

// ---------------------------------------------------------------- V transpose (bf16)
// vb [b][s][head*64+n]  ->  vT [b][head][n(64)][s(1024)]
__global__ __launch_bounds__(256) void v_transpose(
    const unsigned short* __restrict__ v, unsigned short* __restrict__ vT) {
  __shared__ unsigned short T[64][72];
  const int t = threadIdx.x;
  const int st0 = blockIdx.x * 64;
  const int hd = blockIdx.y, b = blockIdx.z;
  const unsigned short* src = v + ((size_t)b * S_ + st0) * D_ + hd * 64;
#pragma unroll
  for (int rep = 0; rep < 4; ++rep) {
    int id = t + rep * 256;
    int s = id >> 4, n4 = (id & 15) * 4;
    short4v val = *(const short4v*)(src + (size_t)s * D_ + n4);
    T[n4 + 0][s] = val[0]; T[n4 + 1][s] = val[1];
    T[n4 + 2][s] = val[2]; T[n4 + 3][s] = val[3];
  }
  __syncthreads();
  unsigned short* dst = vT + ((size_t)(b * NH_ + hd) * 64) * S_ + st0;
#pragma unroll
  for (int rep = 0; rep < 2; ++rep) {
    int id = t + rep * 256;
    int n = id >> 3, s8 = (id & 7) * 8;
    unsigned short tmp[8];
#pragma unroll
    for (int u2 = 0; u2 < 8; ++u2) tmp[u2] = T[n][s8 + u2];
    *(short8v*)(dst + (size_t)n * S_ + s8) = *(short8v*)tmp;
  }
}

// ---------------------------------------------------------------- MFMA flash attention
// grid = 2048 linear, swizzled: xcd=id%8, slot=id/8, qt=slot%8,
// pair=(slot/8)*8+xcd.  The 8 qt-blocks of a pair occupy 64 CONSECUTIVE ids on
// ONE XCD -> K/V (256 KB/pair) L2-resident while all its readers run.
// No-max softmax (logits hard-bounded ~6); K register-double-buffered.
__global__ __launch_bounds__(256) void attn_mfma(
    const unsigned short* __restrict__ qb, const unsigned short* __restrict__ kb,
    const unsigned short* __restrict__ vT, unsigned short* __restrict__ out) {
  __shared__ unsigned short P[4][32][72];
  const int t = threadIdx.x;
  const int w = t >> 6;
  const int L = t & 63;
  const int c = L & 15;
  const int g = L >> 4;
  const int id = blockIdx.x;
  const int xcd = id & 7, slot = id >> 3;
  const int qt = slot & 7;
  const int pair = (slot >> 3) * 8 + xcd;
  const int b = pair >> 4, hd = pair & 15;
  const size_t mrow0 = (size_t)b * S_ + qt * 128 + w * 32;
  const int dcol0 = hd * 64;

  short8v aq[2][2];
#pragma unroll
  for (int i = 0; i < 2; ++i)
#pragma unroll
    for (int st = 0; st < 2; ++st)
      aq[i][st] = *(const short8v*)(qb + (mrow0 + 16 * i + c) * D_ + dcol0 + 32 * st + 8 * g);

  float4v oacc[2][4];
  float l_run[2][4];
#pragma unroll
  for (int i = 0; i < 2; ++i)
#pragma unroll
    for (int r = 0; r < 4; ++r) l_run[i][r] = 0.f;
#pragma unroll
  for (int i = 0; i < 2; ++i)
#pragma unroll
    for (int jv = 0; jv < 4; ++jv) oacc[i][jv] = (float4v){0.f, 0.f, 0.f, 0.f};

  const unsigned short* vbase = vT + (size_t)(b * NH_ + hd) * 64 * S_;
  const unsigned short* kbb = kb + (size_t)b * S_ * D_ + dcol0;

  short8v kf[2][4][2];
#pragma unroll
  for (int j = 0; j < 4; ++j) {
    const unsigned short* kr = kbb + (size_t)(16 * j + c) * D_ + 8 * g;
    kf[0][j][0] = *(const short8v*)(kr);
    kf[0][j][1] = *(const short8v*)(kr + 32);
  }

#pragma unroll 2
  for (int kt = 0; kt < 16; ++kt) {
    const int cur = kt & 1;
    if (kt < 15) {
#pragma unroll
      for (int j = 0; j < 4; ++j) {
        const unsigned short* kr = kbb + (size_t)((kt + 1) * 64 + 16 * j + c) * D_ + 8 * g;
        kf[cur ^ 1][j][0] = *(const short8v*)(kr);
        kf[cur ^ 1][j][1] = *(const short8v*)(kr + 32);
      }
    }
    short8v vf[4][2];
#pragma unroll
    for (int jv = 0; jv < 4; ++jv) {
      const unsigned short* vr = vbase + (size_t)(16 * jv + c) * S_ + kt * 64 + 8 * g;
      vf[jv][0] = *(const short8v*)(vr);
      vf[jv][1] = *(const short8v*)(vr + 32);
    }
    float4v sacc[2][4];
#pragma unroll
    for (int i = 0; i < 2; ++i)
#pragma unroll
      for (int j = 0; j < 4; ++j) sacc[i][j] = (float4v){0.f, 0.f, 0.f, 0.f};
#pragma unroll
    for (int j = 0; j < 4; ++j)
#pragma unroll
      for (int i = 0; i < 2; ++i) {
        sacc[i][j] = __builtin_amdgcn_mfma_f32_16x16x32_bf16(aq[i][0], kf[cur][j][0], sacc[i][j], 0, 0, 0);
        sacc[i][j] = __builtin_amdgcn_mfma_f32_16x16x32_bf16(aq[i][1], kf[cur][j][1], sacc[i][j], 0, 0, 0);
      }
#pragma unroll
    for (int i = 0; i < 2; ++i)
#pragma unroll
      for (int r = 0; r < 4; ++r) {
        float ps = 0.f;
#pragma unroll
        for (int j = 0; j < 4; ++j) {
          float p = __expf(sacc[i][j][r]);
          ps += p;
          P[w][16 * i + 4 * g + r][16 * j + c] = f2bf(p);
        }
        l_run[i][r] += ps;
      }
    short8v ap[2][2];
#pragma unroll
    for (int i = 0; i < 2; ++i)
#pragma unroll
      for (int st = 0; st < 2; ++st) {
        const short4v* pp = (const short4v*)&P[w][16 * i + c][32 * st + 8 * g];
        short4v lo = pp[0];
        short4v hi = pp[1];
        short8v f;
        f[0] = lo[0]; f[1] = lo[1]; f[2] = lo[2]; f[3] = lo[3];
        f[4] = hi[0]; f[5] = hi[1]; f[6] = hi[2]; f[7] = hi[3];
        ap[i][st] = f;
      }
#pragma unroll
    for (int jv = 0; jv < 4; ++jv)
#pragma unroll
      for (int i = 0; i < 2; ++i) {
        oacc[i][jv] = __builtin_amdgcn_mfma_f32_16x16x32_bf16(ap[i][0], vf[jv][0], oacc[i][jv], 0, 0, 0);
        oacc[i][jv] = __builtin_amdgcn_mfma_f32_16x16x32_bf16(ap[i][1], vf[jv][1], oacc[i][jv], 0, 0, 0);
      }
  }
#pragma unroll
  for (int i = 0; i < 2; ++i)
#pragma unroll
    for (int r = 0; r < 4; ++r) {
      float ls = l_run[i][r];
      ls += __shfl_xor(ls, 1);
      ls += __shfl_xor(ls, 2);
      ls += __shfl_xor(ls, 4);
      ls += __shfl_xor(ls, 8);
      float inv = 1.f / ls;
      size_t row = mrow0 + 16 * i + 4 * g + r;
#pragma unroll
      for (int jv = 0; jv < 4; ++jv)
        out[row * D_ + dcol0 + 16 * jv + c] = f2bf(oacc[i][jv][r] * inv);
    }
}

// ---------------------------------------------------------------- launch
// Workspace (peak 168.03 MB < 192 MB proven):
//   [0,32)MB xb (reused as ob after QKV gemms) | [32,64) qb | [64,96) kb
//   [96,128) vb | [128,160) vT | [160,168) wqb,wkb,wvb,wob | [168,+32KB) tables
extern "C" void kernel_launch(void* const* d_in, const int* in_sizes, int n_in,
                              void* d_out, int out_size, void* d_ws, size_t ws_size,
                              hipStream_t stream) {
  const float* x  = (const float*)d_in[0];
  const float* Wq = (const float*)d_in[1];
  const float* bq = (const float*)d_in[2];
  const float* Wk = (const float*)d_in[3];
  const float* bk = (const float*)d_in[4];
  const float* Wv = (const float*)d_in[5];
  const float* bv = (const float*)d_in[6];
  const float* Wo = (const float*)d_in[7];
  const float* bo = (const float*)d_in[8];
  float* out = (float*)d_out;

  char* ws = (char*)d_ws;
  const size_t SZ2 = (size_t)M_TOT * D_ * 2;   // 32 MB
  unsigned short* xb = (unsigned short*)(ws);
  unsigned short* ob = xb;                               // alias: free after QKV gemms
  unsigned short* qb = (unsigned short*)(ws + SZ2);
  unsigned short* kb = (unsigned short*)(ws + 2 * SZ2);
  unsigned short* vb = (unsigned short*)(ws + 3 * SZ2);
  unsigned short* vT = (unsigned short*)(ws + 4 * SZ2);
  unsigned short* wqb = (unsigned short*)(ws + 5 * SZ2);
  unsigned short* wkb = wqb + (size_t)D_ * D_;
  unsigned short* wvb = wkb + (size_t)D_ * D_;
  unsigned short* wob = wvb + (size_t)D_ * D_;
  float* cos1 = (float*)(ws + 5 * SZ2 + 4 * (size_t)D_ * D_ * 2);
  float* sin1 = cos1 + S_ * 8;
  float* cos2 = sin1 + S_ * 8;
  float* sin2 = cos2 + 384;

  build_tables<<<34, 256, 0, stream>>>(cos1, sin1, cos2, sin2);

  f32_to_bf16<<<M_TOT * D_ / 4 / 256, 256, 0, stream>>>(x, xb, M_TOT * D_ / 4);
  w4_to_bf16<<<dim3(D_ * D_ / 4 / 256, 4), 256, 0, stream>>>(Wq, Wk, Wv, Wo, wqb);

  gemm_mfma<true><<<1024, 256, 0, stream>>>(xb, wqb, bq, qb);
  gemm_mfma<true><<<1024, 256, 0, stream>>>(xb, wkb, bk, kb);
  gemm_mfma<true><<<1024, 256, 0, stream>>>(xb, wvb, bv, vb);

  const int rope_blocks = (M_TOT * 512) / 256;
  rope_inplace<<<rope_blocks, 256, 0, stream>>>(qb, cos1, sin1, cos2, sin2, 0.125f);
  rope_inplace<<<rope_blocks, 256, 0, stream>>>(kb, cos1, sin1, cos2, sin2, 1.0f);
  v_transpose<<<dim3(16, 16, 16), 256, 0, stream>>>(vb, vT);

  attn_mfma<<<2048, 256, 0, stream>>>(qb, kb, vT, ob);

  gemm_mfma<false><<<1024, 256, 0, stream>>>(ob, wob, bo, out);
}